// Round 3
// baseline (635.198 us; speedup 1.0000x reference)
//
#include <hip/hip_runtime.h>

// ---------------------------------------------------------------------------
// Attention (Bahdanau): B=32, S=2048, H=512, 2H=1024, 4H=2048
//   u[b,h]      = bias[h] + dot(hidden[b,:1024], W[h,:1024])      (fp32, tiny)
//   scores[b,s] = sum_h v[h]*tanh(u[b,h] + dot(enc[b,s,:], W[h,1024:]))
//   attn        = softmax_s(scores);  context[b,d] = sum_s attn[b,s]*enc[b,s,d]
// bf16 MFMA 16x16x32 with hi/lo split (3 MFMAs) for ~fp32 accuracy.
// R3: 128s x 256h block tile, mt=4 x nt=4 per wave (16 ds_read_b128 / 48 MFMA),
// truncation-based A conversion with v_perm packing (3 VALU ops/float).
// ---------------------------------------------------------------------------

typedef __attribute__((ext_vector_type(8))) short short8;
typedef __attribute__((ext_vector_type(4))) float f4;
typedef __attribute__((ext_vector_type(4))) unsigned int uint4v;

__device__ __forceinline__ unsigned short bf16_rn(float x) {
    unsigned int u = __float_as_uint(x);
    return (unsigned short)((u + 0x7FFFu + ((u >> 16) & 1u)) >> 16);
}
__device__ __forceinline__ float bf16_to_f(unsigned short h) {
    return __uint_as_float(((unsigned int)h) << 16);
}
// (bf16_trunc(b)<<16) | bf16_trunc(a) in ONE v_perm
__device__ __forceinline__ unsigned int pack2_trunc(float a, float b) {
    return __builtin_amdgcn_perm(__float_as_uint(b), __float_as_uint(a), 0x07060302u);
}
__device__ __forceinline__ float trunc_hi(float x) {
    return __uint_as_float(__float_as_uint(x) & 0xFFFF0000u);
}
__device__ __forceinline__ void gload_lds16(const void* g, void* l) {
    __builtin_amdgcn_global_load_lds(
        (const __attribute__((address_space(1))) unsigned int*)g,
        (__attribute__((address_space(3))) unsigned int*)l, 16, 0, 0);
}

// ---------------------------------------------------------------------------
// Kernel 1: u[b,h] (blocks 0..63) + W2 bf16 hi/lo fragment-major pack (64..319)
// Pack layout: chunk g = kk*2048 + nt*64 + q*16 + c  holds
//   W[h=nt*16+c][1024 + kk*32 + q*8 + j], j=0..7  (8 bf16 = 16B)
// ---------------------------------------------------------------------------
__global__ __launch_bounds__(256) void prep_kernel(
    const float* __restrict__ hidden, const float* __restrict__ W,
    const float* __restrict__ bias, float* __restrict__ u,
    unsigned short* __restrict__ w2hi, unsigned short* __restrict__ w2lo) {
    if (blockIdx.x < 64) {
        int t = blockIdx.x * 256 + threadIdx.x;   // 0..16383
        int b = t >> 9, h = t & 511;
        const f4* wr = (const f4*)(W + (size_t)h * 2048);
        const f4* hr = (const f4*)(hidden + (size_t)b * 1024);
        float acc = bias[h];
        #pragma unroll 4
        for (int i = 0; i < 256; ++i) {
            f4 w4 = wr[i]; f4 h4 = hr[i];
            acc += w4[0]*h4[0] + w4[1]*h4[1] + w4[2]*h4[2] + w4[3]*h4[3];
        }
        u[t] = acc;
    } else {
        int g = (blockIdx.x - 64) * 256 + threadIdx.x;   // 0..65535 chunks
        int kk = g >> 11, id = g & 2047;
        int nt = id >> 6, q = (id >> 4) & 3, c = id & 15;
        int h = nt * 16 + c;
        const float* src = W + (size_t)h * 2048 + 1024 + kk * 32 + q * 8;
        short8 vhi, vlo;
        #pragma unroll
        for (int j = 0; j < 8; ++j) {
            float x = src[j];
            unsigned short hb = bf16_rn(x);
            unsigned short lb = bf16_rn(x - bf16_to_f(hb));
            vhi[j] = (short)hb; vlo[j] = (short)lb;
        }
        ((short8*)w2hi)[g] = vhi;
        ((short8*)w2lo)[g] = vlo;
    }
}

// ---------------------------------------------------------------------------
// Kernel 2: fused partial scores. Block = 128 s-rows x 256 h (one h-half),
// 512 threads (8 waves). Wave wl: m-half = wl>>2 (64 rows), n-quarter = wl&3
// (64 cols); per wave mt=4 x nt=4 tiles, 3 MFMAs each.
// grid 1024: sblk = blockIdx.x>>1 (enc tile shared by hh pair), hh = &1.
// LDS = 8+8+16+16+1+1+2 = 52KB; VGPR-capped 2 blocks/CU.
// ---------------------------------------------------------------------------
__global__ __launch_bounds__(512, 4) void score_kernel(
    const float* __restrict__ enc, const unsigned short* __restrict__ w2hi,
    const unsigned short* __restrict__ w2lo, const float* __restrict__ u,
    const float* __restrict__ v, float* __restrict__ scores_part) {
    __shared__ short Ahi[4096], Alo[4096];     // 128 rows x 32 k, chunk-major
    __shared__ short Bhi[8192], Blo[8192];     // 256 h  x 32 k, chunk-major
    __shared__ float u_s[256], v_s[256];
    __shared__ float partial[4][128];

    const int tid  = threadIdx.x;
    const int wl   = tid >> 6, lane = tid & 63;
    const int q    = lane >> 4, m = lane & 15;
    const int half = wl >> 2, nq = wl & 3;
    const int sblk = blockIdx.x >> 1, hh = blockIdx.x & 1;
    const int row0 = sblk * 128;
    const int b    = row0 >> 11;
    const float* encB = enc + (size_t)row0 * 1024;

    if (tid < 256) {
        u_s[tid] = u[(b << 9) + (hh << 8) + tid];
        v_s[tid] = v[(hh << 8) + tid];
    }

    f4 acc[4][4];
    #pragma unroll
    for (int mt = 0; mt < 4; ++mt)
        #pragma unroll
        for (int nt = 0; nt < 4; ++nt) acc[mt][nt] = (f4){0.f, 0.f, 0.f, 0.f};

    // A staging: thread t stages chunk t: row = (t>>6)*16 + (t&15), k = ((t>>4)&3)*8
    const int arow = ((tid >> 6) << 4) + (tid & 15);
    const int akof = ((tid >> 4) & 3) << 3;
    const float* aBase = encB + (size_t)arow * 1024 + akof;

    for (int kk = 0; kk < 32; ++kk) {
        __syncthreads();
        // --- stage A (enc) fp32 -> bf16 hi/lo via truncation, 8 floats/thread
        {
            f4 x0 = *(const f4*)(aBase + (kk << 5));
            f4 x1 = *(const f4*)(aBase + (kk << 5) + 4);
            uint4v hp, lp;
            hp[0] = pack2_trunc(x0[0], x0[1]);
            hp[1] = pack2_trunc(x0[2], x0[3]);
            hp[2] = pack2_trunc(x1[0], x1[1]);
            hp[3] = pack2_trunc(x1[2], x1[3]);
            lp[0] = pack2_trunc(x0[0] - trunc_hi(x0[0]), x0[1] - trunc_hi(x0[1]));
            lp[1] = pack2_trunc(x0[2] - trunc_hi(x0[2]), x0[3] - trunc_hi(x0[3]));
            lp[2] = pack2_trunc(x1[0] - trunc_hi(x1[0]), x1[1] - trunc_hi(x1[1]));
            lp[3] = pack2_trunc(x1[2] - trunc_hi(x1[2]), x1[3] - trunc_hi(x1[3]));
            ((uint4v*)Ahi)[tid] = hp;
            ((uint4v*)Alo)[tid] = lp;
        }
        // --- stage B (W2 packed bf16) via global_load_lds: 16KB hi + 16KB lo
        {
            const size_t srcOff = (size_t)kk * 32768 + (hh << 14) + (wl << 11) + lane * 16;
            #pragma unroll
            for (int i = 0; i < 2; ++i) {
                unsigned int off = (unsigned int)((wl << 11) + (i << 10));   // bytes
                gload_lds16((const char*)w2hi + srcOff + (i << 10), (char*)Bhi + off);
                gload_lds16((const char*)w2lo + srcOff + (i << 10), (char*)Blo + off);
            }
        }
        __syncthreads();
        // --- compute: 4 m-tiles x 4 n-tiles x 3 MFMAs
        short8 ah[4], al[4];
        #pragma unroll
        for (int mt = 0; mt < 4; ++mt) {
            int idx = ((((half << 2) + mt) << 2) + q) * 16 + m;
            ah[mt] = ((short8*)Ahi)[idx];
            al[mt] = ((short8*)Alo)[idx];
        }
        #pragma unroll
        for (int nt = 0; nt < 4; ++nt) {
            int ntg = (nq << 2) + nt;
            int bidx = ((ntg << 2) + q) * 16 + m;
            short8 bh = ((short8*)Bhi)[bidx];
            short8 bl = ((short8*)Blo)[bidx];
            #pragma unroll
            for (int mt = 0; mt < 4; ++mt) {
                acc[mt][nt] = __builtin_amdgcn_mfma_f32_16x16x32_bf16(ah[mt], bh, acc[mt][nt], 0, 0, 0);
                acc[mt][nt] = __builtin_amdgcn_mfma_f32_16x16x32_bf16(ah[mt], bl, acc[mt][nt], 0, 0, 0);
                acc[mt][nt] = __builtin_amdgcn_mfma_f32_16x16x32_bf16(al[mt], bh, acc[mt][nt], 0, 0, 0);
            }
        }
    }
    // --- epilogue: tanh, v-weight, reduce over this block's 256 h
    #pragma unroll
    for (int mt = 0; mt < 4; ++mt) {
        #pragma unroll
        for (int reg = 0; reg < 4; ++reg) {
            float ssum = 0.f;
            #pragma unroll
            for (int nt = 0; nt < 4; ++nt) {
                int hl = (nq << 6) + (nt << 4) + m;
                float e = tanhf(u_s[hl] + acc[mt][nt][reg]);
                ssum += v_s[hl] * e;
            }
            ssum += __shfl_xor(ssum, 1);
            ssum += __shfl_xor(ssum, 2);
            ssum += __shfl_xor(ssum, 4);
            ssum += __shfl_xor(ssum, 8);
            if (m == 0) partial[nq][(half << 6) + (mt << 4) + (q << 2) + reg] = ssum;
        }
    }
    __syncthreads();
    if (tid < 128) {
        float s = partial[0][tid] + partial[1][tid] + partial[2][tid] + partial[3][tid];
        scores_part[(hh << 16) + row0 + tid] = s;
    }
}

// ---------------------------------------------------------------------------
// Kernel 3: per-(b, 64-row s-chunk) softmax + partial context, 1024 blocks
// ---------------------------------------------------------------------------
__global__ __launch_bounds__(256) void ctx_partial_kernel(
    const float* __restrict__ enc, const float* __restrict__ scores_part,
    float* __restrict__ partials) {
    __shared__ float p_s[2048];
    __shared__ float wredm[4], wreds[4];
    const int t = threadIdx.x;
    const int b = blockIdx.x >> 5, sc = blockIdx.x & 31;
    const int wid = t >> 6, lane = t & 63;
    const float* s0 = scores_part + ((size_t)b << 11);
    const float* s1 = s0 + 65536;

    float vals[8];
    float mx = -1e30f;
    #pragma unroll
    for (int i = 0; i < 8; ++i) {
        int idx = t + (i << 8);
        vals[i] = s0[idx] + s1[idx];
        mx = fmaxf(mx, vals[i]);
    }
    #pragma unroll
    for (int off = 1; off < 64; off <<= 1) mx = fmaxf(mx, __shfl_xor(mx, off));
    if (lane == 0) wredm[wid] = mx;
    __syncthreads();
    mx = fmaxf(fmaxf(wredm[0], wredm[1]), fmaxf(wredm[2], wredm[3]));

    float lsum = 0.f;
    #pragma unroll
    for (int i = 0; i < 8; ++i) {
        float e = __expf(vals[i] - mx);
        p_s[t + (i << 8)] = e;
        lsum += e;
    }
    #pragma unroll
    for (int off = 1; off < 64; off <<= 1) lsum += __shfl_xor(lsum, off);
    if (lane == 0) wreds[wid] = lsum;
    __syncthreads();
    const float inv = 1.f / (wreds[0] + wreds[1] + wreds[2] + wreds[3]);

    f4 a = (f4){0.f, 0.f, 0.f, 0.f};
    const f4* erow = ((const f4*)(enc + ((size_t)b * 2048 + (sc << 6)) * 1024)) + t;
    #pragma unroll 4
    for (int i = 0; i < 64; ++i) {
        float p = p_s[(sc << 6) + i] * inv;
        f4 e = erow[(size_t)i << 8];
        a += p * e;
    }
    f4* dst = (f4*)(partials + (((size_t)(sc << 5) + b) << 10));
    dst[t] = a;
}

// ---------------------------------------------------------------------------
// Kernel 4: reduce 32 s-chunk partials -> context
// ---------------------------------------------------------------------------
__global__ __launch_bounds__(256) void ctx_reduce_kernel(
    const float* __restrict__ partials, float* __restrict__ out) {
    int i = blockIdx.x * 256 + threadIdx.x;   // 0..32767  (b*1024 + d)
    float s = 0.f;
    #pragma unroll
    for (int sc = 0; sc < 32; ++sc) s += partials[sc * 32768 + i];
    out[i] = s;
}

// ---------------------------------------------------------------------------
extern "C" void kernel_launch(void* const* d_in, const int* in_sizes, int n_in,
                              void* d_out, int out_size, void* d_ws, size_t ws_size,
                              hipStream_t stream) {
    const float* hidden = (const float*)d_in[0];   // [32,1024]
    const float* enc    = (const float*)d_in[1];   // [32,2048,1024]
    const float* W      = (const float*)d_in[2];   // [512,2048]
    const float* bias   = (const float*)d_in[3];   // [512]
    const float* v      = (const float*)d_in[4];   // [512]
    float* out = (float*)d_out;                    // [32,1024]
    char* ws = (char*)d_ws;

    // ws layout (bytes):
    float* u              = (float*)(ws);                    //    65536
    float* scores_part    = (float*)(ws + 65536);            //   524288 (2 halves)
    float* partials       = (float*)(ws + 589824);           //  4194304
    unsigned short* w2hi  = (unsigned short*)(ws + 4784128); //  1048576
    unsigned short* w2lo  = (unsigned short*)(ws + 5832704); //  1048576  (~6.9MB)

    prep_kernel<<<320, 256, 0, stream>>>(hidden, W, bias, u, w2hi, w2lo);
    score_kernel<<<1024, 512, 0, stream>>>(enc, w2hi, w2lo, u, v, scores_part);
    ctx_partial_kernel<<<1024, 256, 0, stream>>>(enc, scores_part, partials);
    ctx_reduce_kernel<<<128, 256, 0, stream>>>(partials, out);
}

// Round 5
// 548.687 us; speedup vs baseline: 1.1577x; 1.1577x over previous
//
#include <hip/hip_runtime.h>

// ---------------------------------------------------------------------------
// Attention (Bahdanau): B=32, S=2048, H=512, 2H=1024, 4H=2048
//   u[b,h]      = bias[h] + dot(hidden[b,:1024], W[h,:1024])      (fp32, tiny)
//   scores[b,s] = sum_h v[h]*tanh(u[b,h] + dot(enc[b,s,:], W[h,1024:]))
//   attn        = softmax_s(scores);  context[b,d] = sum_s attn[b,s]*enc[b,s,d]
// R5 (= R4 with pkrtz type fix): f16 MFMA 32x32x16, A split hi/lo (pkrtz),
// B single f16 RN -> 2 MFMAs per tile, half the B traffic. Wave tile 64x64
// (mt2 x nt2), 256-thr blocks, no spills.
// ---------------------------------------------------------------------------

typedef __fp16   half2v __attribute__((ext_vector_type(2)));   // pkrtz result type
typedef _Float16 half8  __attribute__((ext_vector_type(8)));   // MFMA operand type
typedef __attribute__((ext_vector_type(4)))  float f4;
typedef __attribute__((ext_vector_type(16))) float f16v;
typedef __attribute__((ext_vector_type(4)))  unsigned int uint4v;

__device__ __forceinline__ void gload_lds16(const void* g, void* l) {
    __builtin_amdgcn_global_load_lds(
        (const __attribute__((address_space(1))) unsigned int*)g,
        (__attribute__((address_space(3))) unsigned int*)l, 16, 0, 0);
}
__device__ __forceinline__ unsigned int bc2(half2v h) {
    return __builtin_bit_cast(unsigned int, h);
}

// ---------------------------------------------------------------------------
// Kernel 1: u[b,h] (blocks 0..63) + W2 f16 fragment-major pack (blocks 64..319)
// Pack: chunk g = kk*2048 + ntg*128 + kh*64 + l  holds 8 f16:
//   W[h = ntg*32 + (l&31)][1024 + kk*32 + kh*16 + (l>>5)*8 + j], j=0..7
// ---------------------------------------------------------------------------
__global__ __launch_bounds__(256) void prep_kernel(
    const float* __restrict__ hidden, const float* __restrict__ W,
    const float* __restrict__ bias, float* __restrict__ u,
    unsigned short* __restrict__ w2) {
    if (blockIdx.x < 64) {
        int t = blockIdx.x * 256 + threadIdx.x;   // 0..16383
        int b = t >> 9, h = t & 511;
        const f4* wr = (const f4*)(W + (size_t)h * 2048);
        const f4* hr = (const f4*)(hidden + (size_t)b * 1024);
        float acc = bias[h];
        #pragma unroll 4
        for (int i = 0; i < 256; ++i) {
            f4 w4 = wr[i]; f4 h4 = hr[i];
            acc += w4[0]*h4[0] + w4[1]*h4[1] + w4[2]*h4[2] + w4[3]*h4[3];
        }
        u[t] = acc;
    } else {
        int g = (blockIdx.x - 64) * 256 + threadIdx.x;   // 0..65535 chunks
        int kk = g >> 11, id = g & 2047;
        int ntg = id >> 7, kh = (id >> 6) & 1, l = id & 63;
        int h = (ntg << 5) + (l & 31);
        int kg = 1024 + (kk << 5) + (kh << 4) + ((l >> 5) << 3);
        const float* src = W + (size_t)h * 2048 + kg;
        f4 x0 = *(const f4*)src;
        f4 x1 = *(const f4*)(src + 4);
        half8 vh;
        #pragma unroll
        for (int j = 0; j < 4; ++j) vh[j] = (_Float16)x0[j];      // RN
        #pragma unroll
        for (int j = 0; j < 4; ++j) vh[4 + j] = (_Float16)x1[j];  // RN
        ((half8*)w2)[g] = vh;
    }
}

// ---------------------------------------------------------------------------
// Kernel 2: fused partial scores. Block = 64 s-rows x 256 h (one h-half),
// 256 threads (4 waves). Wave wl: n-quarter (64 h), all 64 rows (mt=2 of 32).
// grid 2048: sblk = blockIdx.x>>1 (enc tile shared by hh pair), hh = &1.
// LDS: Ahi 4K + Alo 4K + B 16K + u 1K + v 1K + partial 1K = 27KB.
// ---------------------------------------------------------------------------
__global__ __launch_bounds__(256, 3) void score_kernel(
    const float* __restrict__ enc, const unsigned short* __restrict__ w2,
    const float* __restrict__ u, const float* __restrict__ v,
    float* __restrict__ scores_part) {
    __shared__ short Ahi[2048], Alo[2048];   // 64 rows x 32 k f16, chunk-major
    __shared__ short Bs[8192];               // 256 h  x 32 k f16, chunk-major
    __shared__ float u_s[256], v_s[256];
    __shared__ float partial[4][64];

    const int tid  = threadIdx.x;
    const int wl   = tid >> 6, lane = tid & 63;
    const int col  = lane & 31;              // MFMA 32x32 col / A row
    const int sblk = blockIdx.x >> 1, hh = blockIdx.x & 1;
    const int row0 = sblk * 64;
    const int b    = row0 >> 11;
    const float* encB = enc + (size_t)row0 * 1024;

    u_s[tid] = u[(b << 9) + (hh << 8) + tid];
    v_s[tid] = v[(hh << 8) + tid];

    f16v acc[2][2];
    #pragma unroll
    for (int mt = 0; mt < 2; ++mt)
        #pragma unroll
        for (int nt = 0; nt < 2; ++nt)
            #pragma unroll
            for (int r = 0; r < 16; ++r) acc[mt][nt][r] = 0.f;

    // A staging: thread t stages chunk t: mt=t>>7, kh=(t>>6)&1, l=t&63
    //   row = mt*32 + (l&31), kbase = kh*16 + (l>>5)*8
    const int s_mt = tid >> 7, s_kh = (tid >> 6) & 1, s_l = tid & 63;
    const int s_row = (s_mt << 5) + (s_l & 31);
    const int s_kb  = (s_kh << 4) + ((s_l >> 5) << 3);
    const float* aSrc = encB + (size_t)s_row * 1024 + s_kb;

    const half8* Ah8 = (const half8*)Ahi;
    const half8* Al8 = (const half8*)Alo;
    const half8* Bh8 = (const half8*)Bs;

    for (int kk = 0; kk < 32; ++kk) {
        // prefetch A source before barrier (hide global latency)
        f4 x0 = *(const f4*)(aSrc + (kk << 5));
        f4 x1 = *(const f4*)(aSrc + (kk << 5) + 4);
        __syncthreads();   // previous iter's LDS reads complete
        // --- stage A: f32 -> f16 hi (pkrtz) + lo (residual, pkrtz)
        {
            half2v h01 = __builtin_amdgcn_cvt_pkrtz(x0[0], x0[1]);
            half2v h23 = __builtin_amdgcn_cvt_pkrtz(x0[2], x0[3]);
            half2v h45 = __builtin_amdgcn_cvt_pkrtz(x1[0], x1[1]);
            half2v h67 = __builtin_amdgcn_cvt_pkrtz(x1[2], x1[3]);
            half2v l01 = __builtin_amdgcn_cvt_pkrtz(x0[0] - (float)h01[0], x0[1] - (float)h01[1]);
            half2v l23 = __builtin_amdgcn_cvt_pkrtz(x0[2] - (float)h23[0], x0[3] - (float)h23[1]);
            half2v l45 = __builtin_amdgcn_cvt_pkrtz(x1[0] - (float)h45[0], x1[1] - (float)h45[1]);
            half2v l67 = __builtin_amdgcn_cvt_pkrtz(x1[2] - (float)h67[0], x1[3] - (float)h67[1]);
            uint4v hp = {bc2(h01), bc2(h23), bc2(h45), bc2(h67)};
            uint4v lp = {bc2(l01), bc2(l23), bc2(l45), bc2(l67)};
            ((uint4v*)Ahi)[tid] = hp;
            ((uint4v*)Alo)[tid] = lp;
        }
        // --- stage B (w2 f16 packed) via global_load_lds: 16KB, contiguous
        {
            const char* bsrc = (const char*)w2 + (size_t)kk * 32768 + (hh << 14)
                               + (wl << 12) + lane * 16;
            char* bdst = (char*)Bs + (wl << 12);
            #pragma unroll
            for (int i = 0; i < 4; ++i)
                gload_lds16(bsrc + (i << 10), bdst + (i << 10));
        }
        __syncthreads();   // staging complete
        // --- compute: 2 kh x (2 mt x 2 nt x 2 hi/lo) MFMAs
        #pragma unroll
        for (int kh = 0; kh < 2; ++kh) {
            half8 ah0 = Ah8[(kh << 6) + lane];
            half8 ah1 = Ah8[128 + (kh << 6) + lane];
            half8 al0 = Al8[(kh << 6) + lane];
            half8 al1 = Al8[128 + (kh << 6) + lane];
            #pragma unroll
            for (int nt = 0; nt < 2; ++nt) {
                int ntl = (wl << 1) + nt;
                half8 b8 = Bh8[((ntl << 1) + kh) * 64 + lane];
                acc[0][nt] = __builtin_amdgcn_mfma_f32_32x32x16_f16(ah0, b8, acc[0][nt], 0, 0, 0);
                acc[0][nt] = __builtin_amdgcn_mfma_f32_32x32x16_f16(al0, b8, acc[0][nt], 0, 0, 0);
                acc[1][nt] = __builtin_amdgcn_mfma_f32_32x32x16_f16(ah1, b8, acc[1][nt], 0, 0, 0);
                acc[1][nt] = __builtin_amdgcn_mfma_f32_32x32x16_f16(al1, b8, acc[1][nt], 0, 0, 0);
            }
        }
    }
    // --- epilogue: tanh, v-weight, reduce over 256 h (block-local)
    // C/D layout 32x32: col = lane&31, row = (reg&3) + 8*(reg>>2) + 4*(lane>>5)
    const int rhalf = (lane >> 5) << 2;
    #pragma unroll
    for (int mt = 0; mt < 2; ++mt) {
        #pragma unroll
        for (int reg = 0; reg < 16; ++reg) {
            float ssum = 0.f;
            #pragma unroll
            for (int nt = 0; nt < 2; ++nt) {
                int hl = (((wl << 1) + nt) << 5) + col;
                float x = u_s[hl] + acc[mt][nt][reg];
                float t = __expf(2.f * x);               // tanh via exp
                float th = 1.f - 2.f / (t + 1.f);
                ssum += v_s[hl] * th;
            }
            ssum += __shfl_xor(ssum, 1);
            ssum += __shfl_xor(ssum, 2);
            ssum += __shfl_xor(ssum, 4);
            ssum += __shfl_xor(ssum, 8);
            ssum += __shfl_xor(ssum, 16);
            if (col == 0)
                partial[wl][(mt << 5) + (reg & 3) + ((reg >> 2) << 3) + rhalf] = ssum;
        }
    }
    __syncthreads();
    if (tid < 64) {
        float s = partial[0][tid] + partial[1][tid] + partial[2][tid] + partial[3][tid];
        scores_part[(hh << 16) + row0 + tid] = s;
    }
}

// ---------------------------------------------------------------------------
// Kernel 3: per-(b, 64-row s-chunk) softmax + partial context, 1024 blocks
// ---------------------------------------------------------------------------
__global__ __launch_bounds__(256) void ctx_partial_kernel(
    const float* __restrict__ enc, const float* __restrict__ scores_part,
    float* __restrict__ partials) {
    __shared__ float p_s[2048];
    __shared__ float wredm[4], wreds[4];
    const int t = threadIdx.x;
    const int b = blockIdx.x >> 5, sc = blockIdx.x & 31;
    const int wid = t >> 6, lane = t & 63;
    const float* s0 = scores_part + ((size_t)b << 11);
    const float* s1 = s0 + 65536;

    float vals[8];
    float mx = -1e30f;
    #pragma unroll
    for (int i = 0; i < 8; ++i) {
        int idx = t + (i << 8);
        vals[i] = s0[idx] + s1[idx];
        mx = fmaxf(mx, vals[i]);
    }
    #pragma unroll
    for (int off = 1; off < 64; off <<= 1) mx = fmaxf(mx, __shfl_xor(mx, off));
    if (lane == 0) wredm[wid] = mx;
    __syncthreads();
    mx = fmaxf(fmaxf(wredm[0], wredm[1]), fmaxf(wredm[2], wredm[3]));

    float lsum = 0.f;
    #pragma unroll
    for (int i = 0; i < 8; ++i) {
        float e = __expf(vals[i] - mx);
        p_s[t + (i << 8)] = e;
        lsum += e;
    }
    #pragma unroll
    for (int off = 1; off < 64; off <<= 1) lsum += __shfl_xor(lsum, off);
    if (lane == 0) wreds[wid] = lsum;
    __syncthreads();
    const float inv = 1.f / (wreds[0] + wreds[1] + wreds[2] + wreds[3]);

    f4 a = (f4){0.f, 0.f, 0.f, 0.f};
    const f4* erow = ((const f4*)(enc + ((size_t)b * 2048 + (sc << 6)) * 1024)) + t;
    #pragma unroll 4
    for (int i = 0; i < 64; ++i) {
        float p = p_s[(sc << 6) + i] * inv;
        f4 e = erow[(size_t)i << 8];
        a += p * e;
    }
    f4* dst = (f4*)(partials + (((size_t)(sc << 5) + b) << 10));
    dst[t] = a;
}

// ---------------------------------------------------------------------------
// Kernel 4: reduce 32 s-chunk partials -> context
// ---------------------------------------------------------------------------
__global__ __launch_bounds__(256) void ctx_reduce_kernel(
    const float* __restrict__ partials, float* __restrict__ out) {
    int i = blockIdx.x * 256 + threadIdx.x;   // 0..32767  (b*1024 + d)
    float s = 0.f;
    #pragma unroll
    for (int sc = 0; sc < 32; ++sc) s += partials[sc * 32768 + i];
    out[i] = s;
}

// ---------------------------------------------------------------------------
extern "C" void kernel_launch(void* const* d_in, const int* in_sizes, int n_in,
                              void* d_out, int out_size, void* d_ws, size_t ws_size,
                              hipStream_t stream) {
    const float* hidden = (const float*)d_in[0];   // [32,1024]
    const float* enc    = (const float*)d_in[1];   // [32,2048,1024]
    const float* W      = (const float*)d_in[2];   // [512,2048]
    const float* bias   = (const float*)d_in[3];   // [512]
    const float* v      = (const float*)d_in[4];   // [512]
    float* out = (float*)d_out;                    // [32,1024]
    char* ws = (char*)d_ws;

    // ws layout (bytes):
    float* u            = (float*)(ws);                    //    65536
    float* scores_part  = (float*)(ws + 65536);            //   524288 (2 halves)
    float* partials     = (float*)(ws + 589824);           //  4194304
    unsigned short* w2  = (unsigned short*)(ws + 4784128); //  1048576  (~5.8MB)

    prep_kernel<<<320, 256, 0, stream>>>(hidden, W, bias, u, w2);
    score_kernel<<<2048, 256, 0, stream>>>(enc, w2, u, v, scores_part);
    ctx_partial_kernel<<<1024, 256, 0, stream>>>(enc, scores_part, partials);
    ctx_reduce_kernel<<<128, 256, 0, stream>>>(partials, out);
}